// Round 5
// baseline (59.360 us; speedup 1.0000x reference)
//
#include <hip/hip_runtime.h>

#define NG     4096
#define NPOSE  2
#define HLOG2E 0.7213475204444817f   // 0.5 * log2(e)

#if __has_builtin(__builtin_amdgcn_exp2f)
#define EXP2F(x) __builtin_amdgcn_exp2f(x)
#else
#define EXP2F(x) exp2f(x)
#endif
#if __has_builtin(__builtin_amdgcn_logf)
#define LOG2F(x) __builtin_amdgcn_logf(x)
#else
#define LOG2F(x) log2f(x)
#endif
#if __has_builtin(__builtin_amdgcn_rcpf)
#define RCPF(x) __builtin_amdgcn_rcpf(x)
#else
#define RCPF(x) (1.0f / (x))
#endif

// ---------------------------------------------------------------------------
// Single fused kernel, 64 blocks x 512 threads.
// Block = one 4-row pixel band of one pose (512 px). Wave w owns 64 px:
// row = band + (w>>1), x = (w&1)*64 + lane. No cross-wave reduction needed.
//
// Phase 1 (cull): 2 rounds; each thread projects 4 gaussians (pos read as
// 3x float4, coalesced) and tests the band box with the conservative bound
//   keep  iff  d2min <= 950     (var_max = 2.5^2, opacity <= 1)
// i.e. dropped gaussians have best-case weight < 2^-109.6; total dropped
// contribution <= 4096 * 2^-109.6 / 1e-8 ~ 4e-22 << pass threshold 7.9e-18.
// Compaction is atomic-free: each wave writes a private 512-entry segment
// of the LDS list using ballot prefix sums (wave-uniform running offset).
//
// Phase 2: every wave walks all 8 segments; per survivor the projection is
// recomputed from globals (wave-uniform addresses -> scalar loads) and
// w = 2^(s2*d2 + log2(op)) accumulated per pixel. Store = num * rcp(den).
// ---------------------------------------------------------------------------
__global__ __launch_bounds__(512) void render_fused(
        const float* __restrict__ pos,
        const float* __restrict__ col,
        const float* __restrict__ opa,
        const float* __restrict__ scl,
        const float* __restrict__ qv,
        const float* __restrict__ tv,
        float* __restrict__ out) {
    __shared__ unsigned short list[NG];
    __shared__ int counts[8];

    const int tid  = threadIdx.x;
    const int lane = tid & 63;
    const int wave = tid >> 6;
    const int blk  = blockIdx.x;          // 0..63
    const int pose = blk >> 5;            // 32 bands per pose
    const int band = (blk & 31) << 2;     // base row of the 4-row band
    const float fx = (float)(((wave & 1) << 6) + lane);
    const float fy = (float)(band + (wave >> 1));
    const float Y0 = (float)band, Y1 = (float)(band + 3);

    // ---- pose transform (block-uniform; scalarized loads) ----
    float q0 = qv[pose * 4 + 0], q1 = qv[pose * 4 + 1];
    float q2 = qv[pose * 4 + 2], q3 = qv[pose * 4 + 3];
    float inrm = RCPF(sqrtf(q0 * q0 + q1 * q1 + q2 * q2 + q3 * q3));
    float w = q0 * inrm, x = q1 * inrm, y = q2 * inrm, z = q3 * inrm;
    float r00 = 1.0f - 2.0f * (y * y + z * z);
    float r01 = 2.0f * (x * y - z * w);
    float r02 = 2.0f * (x * z + y * w);
    float r10 = 2.0f * (x * y + z * w);
    float r11 = 1.0f - 2.0f * (x * x + z * z);
    float r12 = 2.0f * (y * z - x * w);
    float r20 = 2.0f * (x * z - y * w);
    float r21 = 2.0f * (y * z + x * w);
    float r22 = 1.0f - 2.0f * (x * x + y * y);
    float t0 = tv[pose * 3 + 0], t1 = tv[pose * 3 + 1], t2 = tv[pose * 3 + 2];

    const float4* __restrict__ pos4 = (const float4*)pos;

    // ---- Phase 1: cull + atomic-free per-wave compaction ----
    int off = 0;                          // wave-uniform running count
#pragma unroll
    for (int r = 0; r < 2; ++r) {
        int t = r * 512 + tid;            // 0..1023 -> gaussians 4t..4t+3
        float4 p0 = pos4[3 * t + 0];
        float4 p1 = pos4[3 * t + 1];
        float4 p2 = pos4[3 * t + 2];
        float gx[4] = {p0.x, p0.w, p1.z, p2.y};
        float gy[4] = {p0.y, p1.x, p1.w, p2.z};
        float gz[4] = {p0.z, p1.y, p2.x, p2.w};
        bool keep[4];
#pragma unroll
        for (int j = 0; j < 4; ++j) {
            float cz = fmaf(r20, gx[j], fmaf(r21, gy[j], fmaf(r22, gz[j], t2)));
            float cx = fmaf(r00, gx[j], fmaf(r01, gy[j], fmaf(r02, gz[j], t0)));
            float cy = fmaf(r10, gx[j], fmaf(r11, gy[j], fmaf(r12, gz[j], t1)));
            float iz  = RCPF(cz);
            float pjx = fmaf(cx * iz, 120.0f, 64.0f);
            float pjy = fmaf(cy * iz, 120.0f, 64.0f);
            float dxm = fmaxf(fmaxf(-pjx, pjx - 127.0f), 0.0f);
            float dym = fmaxf(fmaxf(Y0 - pjy, pjy - Y1), 0.0f);
            keep[j] = fmaf(dxm, dxm, dym * dym) <= 950.0f;
        }
#pragma unroll
        for (int j = 0; j < 4; ++j) {
            unsigned long long m = __ballot(keep[j]);
            if (keep[j]) {
                int p = off + __popcll(m & ((1ull << lane) - 1ull));
                list[(wave << 9) + p] = (unsigned short)(4 * t + j);
            }
            off += __popcll(m);
        }
    }
    if (lane == 0) counts[wave] = off;
    __syncthreads();

    // ---- Phase 2: survivor loop (each wave does all survivors, own pixels) --
    float accR = 0.0f, accG = 0.0f, accB = 0.0f, accD = 0.0f;
    for (int seg = 0; seg < 8; ++seg) {
        int c = __builtin_amdgcn_readfirstlane(counts[seg]);
        for (int i = 0; i < c; ++i) {
            int g = __builtin_amdgcn_readfirstlane((int)list[(seg << 9) + i]);
            float px = pos[g * 3 + 0], py = pos[g * 3 + 1], pz = pos[g * 3 + 2];
            float cz = fmaf(r20, px, fmaf(r21, py, fmaf(r22, pz, t2)));
            float cx = fmaf(r00, px, fmaf(r01, py, fmaf(r02, pz, t0)));
            float cy = fmaf(r10, px, fmaf(r11, py, fmaf(r12, pz, t1)));
            float iz  = RCPF(cz);
            float pjx = fmaf(cx * iz, 120.0f, 64.0f);
            float pjy = fmaf(cy * iz, 120.0f, 64.0f);
            float sc  = scl[g];
            float s2  = -HLOG2E * RCPF(sc * sc);
            float lop = LOG2F(opa[g]);
            float cr = col[g * 3 + 0], cg = col[g * 3 + 1], cb = col[g * 3 + 2];
            float dx = fx - pjx;
            float dy = fy - pjy;
            float d2 = fmaf(dx, dx, dy * dy);
            float e  = EXP2F(fmaf(d2, s2, lop));  // opacity * exp(-0.5*d2/var)
            accD += e;
            accR = fmaf(e, cr, accR);
            accG = fmaf(e, cg, accG);
            accB = fmaf(e, cb, accB);
        }
    }

    // ---- store (tiled layout) ----
    float iden = RCPF(accD + 1e-8f);
    int pid = (band + (wave >> 1)) * 128 + ((wave & 1) << 6) + lane;
    int tl  = pid >> 10;          // tile index
    int pl  = pid & 1023;         // position within tile
    float* o = out + ((size_t)(pose * 16 + tl) * 3) * 1024 + pl;
    o[0]    = accR * iden;
    o[1024] = accG * iden;
    o[2048] = accB * iden;
}

extern "C" void kernel_launch(void* const* d_in, const int* in_sizes, int n_in,
                              void* d_out, int out_size, void* d_ws, size_t ws_size,
                              hipStream_t stream) {
    const float* pos = (const float*)d_in[0];
    const float* col = (const float*)d_in[1];
    const float* opa = (const float*)d_in[2];
    const float* scl = (const float*)d_in[3];
    const float* qv  = (const float*)d_in[4];
    const float* tv  = (const float*)d_in[5];
    float* out = (float*)d_out;

    render_fused<<<NPOSE * 32, 512, 0, stream>>>(pos, col, opa, scl, qv, tv, out);
}

// Round 6
// 10.370 us; speedup vs baseline: 5.7244x; 5.7244x over previous
//
#include <hip/hip_runtime.h>

#define NG     4096
#define NPOSE  2
#define HLOG2E 0.7213475204444817f   // 0.5 * log2(e)
#define SEGCAP 128                   // payload capacity per wave segment

#if __has_builtin(__builtin_amdgcn_exp2f)
#define EXP2F(x) __builtin_amdgcn_exp2f(x)
#else
#define EXP2F(x) exp2f(x)
#endif
#if __has_builtin(__builtin_amdgcn_logf)
#define LOG2F(x) __builtin_amdgcn_logf(x)
#else
#define LOG2F(x) log2f(x)
#endif
#if __has_builtin(__builtin_amdgcn_rcpf)
#define RCPF(x) __builtin_amdgcn_rcpf(x)
#else
#define RCPF(x) (1.0f / (x))
#endif

// ---------------------------------------------------------------------------
// Fused single kernel, 256 blocks x 512 threads. Block = one image row of one
// pose. Waves: pg = wave&1 (x-half 0..63 / 64..127), slice = wave>>1 (0..3).
//
// Phase 1 (cull + payload): 2 rounds; each thread projects 4 gaussians
// (pos and scl read as float4, coalesced) and tests the exact-variance row
// bound:  keep iff HLOG2E*d2min <= 110*var  (opacity<=1 only shrinks w), so
// dropped gaussians contribute < 2^-110 each; total dropped
// <= 4096*2^-110/1e-8 ~ 3e-22 << pass threshold 7.9e-18.
// Keeping threads write the FULL payload {pjx,pjy,s2,log2(op)},{r,g,b} into
// compacted per-wave LDS segments (atomic-free ballot prefix). This removes
// all global loads from the phase-2 critical path — the R5 regression was a
// ~600-cycle serial global-load chain per survivor (90us at 0.4% VALUBusy).
// Overflow beyond SEGCAP spills indices to LDS and is handled by a correct
// global-recompute path (never triggered for this input: observed L/segment
// ~12-50 vs cap 128).
//
// Phase 2: slice s processes survivors i = s, s+4, ... of each segment via
// two broadcast ds_read_b128 + ~12 VALU. Phase 3: LDS reduce over the 4
// slices, divide once, tiled store.
// ---------------------------------------------------------------------------
__global__ __launch_bounds__(512) void render_fused(
        const float* __restrict__ pos,
        const float* __restrict__ col,
        const float* __restrict__ opa,
        const float* __restrict__ scl,
        const float* __restrict__ qv,
        const float* __restrict__ tv,
        float* __restrict__ out) {
    __shared__ float4 pG[8 * SEGCAP];          // {pjx, pjy, s2, log2(op)}
    __shared__ float4 pC[8 * SEGCAP];          // {r, g, b, 0}
    __shared__ unsigned short spill[8][512 - SEGCAP];
    __shared__ int counts[8];
    __shared__ float4 red[8][64];

    const int tid  = threadIdx.x;
    const int lane = tid & 63;
    const int wave = tid >> 6;
    const int blk  = blockIdx.x;           // 0..255
    const int pose = blk >> 7;             // 128 rows per pose
    const int row  = blk & 127;
    const int pg_  = wave & 1;
    const int slice = wave >> 1;
    const float fx = (float)((pg_ << 6) + lane);
    const float fy = (float)row;

    // ---- pose transform (block-uniform; scalarized loads) ----
    float q0 = qv[pose * 4 + 0], q1 = qv[pose * 4 + 1];
    float q2 = qv[pose * 4 + 2], q3 = qv[pose * 4 + 3];
    float inrm = RCPF(sqrtf(q0 * q0 + q1 * q1 + q2 * q2 + q3 * q3));
    float w = q0 * inrm, x = q1 * inrm, y = q2 * inrm, z = q3 * inrm;
    float r00 = 1.0f - 2.0f * (y * y + z * z);
    float r01 = 2.0f * (x * y - z * w);
    float r02 = 2.0f * (x * z + y * w);
    float r10 = 2.0f * (x * y + z * w);
    float r11 = 1.0f - 2.0f * (x * x + z * z);
    float r12 = 2.0f * (y * z - x * w);
    float r20 = 2.0f * (x * z - y * w);
    float r21 = 2.0f * (y * z + x * w);
    float r22 = 1.0f - 2.0f * (x * x + y * y);
    float t0 = tv[pose * 3 + 0], t1 = tv[pose * 3 + 1], t2 = tv[pose * 3 + 2];

    const float4* __restrict__ pos4 = (const float4*)pos;
    const float4* __restrict__ scl4 = (const float4*)scl;

    // ---- Phase 1: cull + payload compaction (atomic-free) ----
    int off = 0;                           // wave-uniform running count
#pragma unroll
    for (int r = 0; r < 2; ++r) {
        int t = r * 512 + tid;             // slot -> gaussians 4t..4t+3
        float4 p0 = pos4[3 * t + 0];
        float4 p1 = pos4[3 * t + 1];
        float4 p2 = pos4[3 * t + 2];
        float4 s4 = scl4[t];
        float gx[4] = {p0.x, p0.w, p1.z, p2.y};
        float gy[4] = {p0.y, p1.x, p1.w, p2.z};
        float gz[4] = {p0.z, p1.y, p2.x, p2.w};
        float sv[4] = {s4.x, s4.y, s4.z, s4.w};
        float pjx[4], pjy[4], var[4];
        bool keep[4];
#pragma unroll
        for (int j = 0; j < 4; ++j) {
            float cz = fmaf(r20, gx[j], fmaf(r21, gy[j], fmaf(r22, gz[j], t2)));
            float cx = fmaf(r00, gx[j], fmaf(r01, gy[j], fmaf(r02, gz[j], t0)));
            float cy = fmaf(r10, gx[j], fmaf(r11, gy[j], fmaf(r12, gz[j], t1)));
            float iz = RCPF(cz);
            pjx[j] = fmaf(cx * iz, 120.0f, 64.0f);
            pjy[j] = fmaf(cy * iz, 120.0f, 64.0f);
            var[j] = sv[j] * sv[j];
            float dxm = fmaxf(fmaxf(-pjx[j], pjx[j] - 127.0f), 0.0f);
            float dy  = pjy[j] - fy;
            float d2m = fmaf(dxm, dxm, dy * dy);
            keep[j] = fmaf(d2m, HLOG2E, -110.0f * var[j]) <= 0.0f;
        }
#pragma unroll
        for (int j = 0; j < 4; ++j) {
            unsigned long long m = __ballot(keep[j]);
            if (keep[j]) {
                int g = 4 * t + j;
                int p = off + __popcll(m & ((1ull << lane) - 1ull));
                if (p < SEGCAP) {
                    float s2  = -HLOG2E * RCPF(var[j]);
                    float lop = LOG2F(opa[g]);
                    int idx = (wave << 7) + p;
                    pG[idx] = make_float4(pjx[j], pjy[j], s2, lop);
                    pC[idx] = make_float4(col[3 * g], col[3 * g + 1],
                                          col[3 * g + 2], 0.0f);
                } else {
                    spill[wave][p - SEGCAP] = (unsigned short)g;
                }
            }
            off += __popcll(m);
        }
    }
    if (lane == 0) counts[wave] = off;
    __syncthreads();

    // ---- Phase 2: survivor loop, all data from LDS (broadcast reads) ----
    float accR = 0.0f, accG = 0.0f, accB = 0.0f, accD = 0.0f;
    for (int seg = 0; seg < 8; ++seg) {
        int c  = __builtin_amdgcn_readfirstlane(counts[seg]);
        int cl = c < SEGCAP ? c : SEGCAP;
#pragma unroll 2
        for (int i = slice; i < cl; i += 4) {
            float4 G = pG[(seg << 7) + i];
            float4 C = pC[(seg << 7) + i];
            float dx = fx - G.x;
            float dy = fy - G.y;
            float d2 = fmaf(dx, dx, dy * dy);
            float e  = EXP2F(fmaf(d2, G.z, G.w));
            accD += e;
            accR = fmaf(e, C.x, accR);
            accG = fmaf(e, C.y, accG);
            accB = fmaf(e, C.z, accB);
        }
        // overflow fallback (correct but slow; never triggered for this input)
        for (int i = SEGCAP + slice; i < c; i += 4) {
            int g = __builtin_amdgcn_readfirstlane(
                        (int)spill[seg][i - SEGCAP]);
            float px = pos[g * 3 + 0], py = pos[g * 3 + 1], pz = pos[g * 3 + 2];
            float cz = fmaf(r20, px, fmaf(r21, py, fmaf(r22, pz, t2)));
            float cx = fmaf(r00, px, fmaf(r01, py, fmaf(r02, pz, t0)));
            float cy = fmaf(r10, px, fmaf(r11, py, fmaf(r12, pz, t1)));
            float iz  = RCPF(cz);
            float pjx = fmaf(cx * iz, 120.0f, 64.0f);
            float pjy = fmaf(cy * iz, 120.0f, 64.0f);
            float sc  = scl[g];
            float s2  = -HLOG2E * RCPF(sc * sc);
            float lop = LOG2F(opa[g]);
            float dx = fx - pjx, dy = fy - pjy;
            float e  = EXP2F(fmaf(fmaf(dx, dx, dy * dy), s2, lop));
            accD += e;
            accR = fmaf(e, col[3 * g + 0], accR);
            accG = fmaf(e, col[3 * g + 1], accG);
            accB = fmaf(e, col[3 * g + 2], accB);
        }
    }

    // ---- Phase 3: reduce across the 4 slices + tiled store ----
    red[wave][lane] = make_float4(accR, accG, accB, accD);
    __syncthreads();
    if (tid < 128) {
        int pg2 = tid >> 6, ln = tid & 63;
        float4 s = red[pg2][ln];
#pragma unroll
        for (int sl = 1; sl < 4; ++sl) {
            float4 t = red[pg2 + 2 * sl][ln];
            s.x += t.x; s.y += t.y; s.z += t.z; s.w += t.w;
        }
        float iden = RCPF(s.w + 1e-8f);
        int pid = row * 128 + pg2 * 64 + ln;
        int tl  = pid >> 10;
        int pl  = pid & 1023;
        float* o = out + ((size_t)(pose * 16 + tl) * 3) * 1024 + pl;
        o[0]    = s.x * iden;
        o[1024] = s.y * iden;
        o[2048] = s.z * iden;
    }
}

extern "C" void kernel_launch(void* const* d_in, const int* in_sizes, int n_in,
                              void* d_out, int out_size, void* d_ws, size_t ws_size,
                              hipStream_t stream) {
    const float* pos = (const float*)d_in[0];
    const float* col = (const float*)d_in[1];
    const float* opa = (const float*)d_in[2];
    const float* scl = (const float*)d_in[3];
    const float* qv  = (const float*)d_in[4];
    const float* tv  = (const float*)d_in[5];
    float* out = (float*)d_out;

    render_fused<<<NPOSE * 128, 512, 0, stream>>>(pos, col, opa, scl, qv, tv, out);
}